// Round 2
// baseline (21424.934 us; speedup 1.0000x reference)
//
#include <hip/hip_runtime.h>
#include <hip/hip_bf16.h>
#include <stdint.h>

// LSTM T=512 B=64 I=H=1024.
// Phase 1: xg = x @ w_ih^T + (b_ih+b_hh)  -- big MFMA GEMM, bf16 out, permuted layout.
// Phase 2: persistent kernel, 256 blocks (1/CU), w_hh slice in LDS, c in regs,
//          4 independent batch-groups, 1 barrier/step (2-level atomic), h double-buffered.

typedef short  short8 __attribute__((ext_vector_type(8)));
typedef float  f32x4  __attribute__((ext_vector_type(4)));

#define T_STEPS 512

__device__ __forceinline__ unsigned short f2bf(float f) {
    uint32_t u = __float_as_uint(f);
    return (unsigned short)((u + 0x7fffu + ((u >> 16) & 1u)) >> 16);
}
__device__ __forceinline__ float bf2f(unsigned short v) {
    return __uint_as_float(((uint32_t)v) << 16);
}
__device__ __forceinline__ float sigf(float x)  { return 1.0f / (1.0f + __expf(-x)); }
__device__ __forceinline__ float tanhf_(float x){ return 1.0f - 2.0f / (__expf(2.0f * x) + 1.0f); }

// ---------------------------------------------------------------- setup
// w_ih -> bf16, bias = b_ih+b_hh, h0 -> bf16 into hbuf[0], zero barrier counters.
__global__ void k_setup(const float* __restrict__ w_ih,
                        const float* __restrict__ b_ih, const float* __restrict__ b_hh,
                        const float* __restrict__ h0,
                        unsigned short* __restrict__ wb, float* __restrict__ bias,
                        unsigned short* __restrict__ hb0, unsigned* __restrict__ cnt) {
    int idx = blockIdx.x * blockDim.x + threadIdx.x;
    int stride = gridDim.x * blockDim.x;
    const float4* w4 = (const float4*)w_ih;
    ushort4* wb4 = (ushort4*)wb;
    for (int i = idx; i < 1048576; i += stride) {       // 4096*1024/4
        float4 v = w4[i];
        wb4[i] = make_ushort4(f2bf(v.x), f2bf(v.y), f2bf(v.z), f2bf(v.w));
    }
    const float4* bi4 = (const float4*)b_ih;
    const float4* bh4 = (const float4*)b_hh;
    float4* bs4 = (float4*)bias;
    for (int i = idx; i < 1024; i += stride) {
        float4 a = bi4[i], b = bh4[i];
        bs4[i] = make_float4(a.x + b.x, a.y + b.y, a.z + b.z, a.w + b.w);
    }
    const float4* h04 = (const float4*)h0;
    ushort4* hb4 = (ushort4*)hb0;
    for (int i = idx; i < 16384; i += stride) {
        float4 v = h04[i];
        hb4[i] = make_ushort4(f2bf(v.x), f2bf(v.y), f2bf(v.z), f2bf(v.w));
    }
    for (int i = idx; i < 6144; i += stride) cnt[i] = 0u;   // cnt1(4096) + cnt2(2048)
}

// ---------------------------------------------------------------- xg GEMM
// out[m][n] = sum_k x[m][k] * w_ih[n][k] + bias[n], m = t*64+b, n = g*1024+j.
// 128x128 tile, BK=64, 256 threads / 4 waves, each wave 4x4 16x16 frags.
// xg layout: [t][lb = bg*64+jg][g][bl*16+jl]  (2 KB contiguous per (t, block)).
__device__ __forceinline__ short8 lds_frag(const unsigned short* base, int row, int kbyte) {
    unsigned off = (unsigned)(row * 128 + kbyte);
    off ^= (unsigned)((row & 7) << 4);
    return *(const short8*)((const char*)base + off);
}

__global__ __launch_bounds__(256) void k_gemm(const float* __restrict__ x,
                                              const unsigned short* __restrict__ wb,
                                              const float* __restrict__ bias,
                                              unsigned short* __restrict__ xg) {
    __shared__ unsigned short As[128 * 64];
    __shared__ unsigned short Bs[128 * 64];
    // XCD-aware swizzle: 8192 blocks -> xcd = orig&7 gets contiguous chunk; 4 n-panels/XCD.
    unsigned orig = blockIdx.x;
    unsigned xcd = orig & 7, idx = orig >> 3;           // idx 0..1023
    unsigned n_t = xcd * 4 + (idx >> 8);                // 0..31
    unsigned m_t = idx & 255;                           // 0..255
    const int m0 = (int)m_t * 128, n0 = (int)n_t * 128;
    const int tid = threadIdx.x;
    const int lane = tid & 63, w = tid >> 6;
    const int wr = w >> 1, wc = w & 1;
    const int r = lane & 15, kq = lane >> 4;

    f32x4 acc[4][4] = {};

    const int ar = tid >> 1, ah = tid & 1;              // staging row / k-half

    for (int k0 = 0; k0 < 1024; k0 += 64) {
        // stage A: x fp32 -> bf16, swizzled
        {
            const float4* src = (const float4*)(x + (size_t)(m0 + ar) * 1024 + k0 + ah * 32);
            unsigned aw_base = (unsigned)(ar * 128 + ah * 64);
            unsigned sw = (unsigned)((ar & 7) << 4);
            #pragma unroll
            for (int i = 0; i < 4; ++i) {
                float4 v0 = src[2 * i], v1 = src[2 * i + 1];
                short8 p;
                p[0] = (short)f2bf(v0.x); p[1] = (short)f2bf(v0.y);
                p[2] = (short)f2bf(v0.z); p[3] = (short)f2bf(v0.w);
                p[4] = (short)f2bf(v1.x); p[5] = (short)f2bf(v1.y);
                p[6] = (short)f2bf(v1.z); p[7] = (short)f2bf(v1.w);
                *(short8*)((char*)As + ((aw_base + i * 16) ^ sw)) = p;
            }
        }
        // stage B: w_ih bf16, swizzled
        {
            const short8* src = (const short8*)(wb + (size_t)(n0 + ar) * 1024 + k0 + ah * 32);
            unsigned bw_base = (unsigned)(ar * 128 + ah * 64);
            unsigned sw = (unsigned)((ar & 7) << 4);
            #pragma unroll
            for (int i = 0; i < 4; ++i) {
                short8 p = src[i];
                *(short8*)((char*)Bs + ((bw_base + i * 16) ^ sw)) = p;
            }
        }
        __syncthreads();
        #pragma unroll
        for (int kk = 0; kk < 2; ++kk) {
            short8 af[4], bfr[4];
            #pragma unroll
            for (int i = 0; i < 4; ++i) af[i]  = lds_frag(As, wr * 64 + i * 16 + r, (kk * 32 + kq * 8) * 2);
            #pragma unroll
            for (int j = 0; j < 4; ++j) bfr[j] = lds_frag(Bs, wc * 64 + j * 16 + r, (kk * 32 + kq * 8) * 2);
            #pragma unroll
            for (int i = 0; i < 4; ++i)
                #pragma unroll
                for (int j = 0; j < 4; ++j)
                    acc[i][j] = __builtin_amdgcn_mfma_f32_16x16x32_bf16(af[i], bfr[j], acc[i][j], 0, 0, 0);
        }
        __syncthreads();
    }

    // epilogue: add bias, write bf16 to permuted xg layout
    const int t_idx = (m0 + wr * 64) >> 6;              // uniform per wave
    const size_t tb = (size_t)t_idx * 256;
    #pragma unroll
    for (int j = 0; j < 4; ++j) {
        int nn = n0 + wc * 64 + j * 16 + r;
        float bsum = bias[nn];
        int g = nn >> 10, jj = nn & 1023;
        int jgx = jj >> 4, jlx = jj & 15;
        #pragma unroll
        for (int i = 0; i < 4; ++i) {                   // i == bg
            size_t off = ((tb + (size_t)i * 64 + jgx) * 4 + g) * 256 + (size_t)(kq * 4) * 16 + jlx;
            #pragma unroll
            for (int q = 0; q < 4; ++q)
                xg[off + (size_t)q * 16] = f2bf(acc[i][j][q] + bsum);
        }
    }
}

// ---------------------------------------------------------------- persistent recurrence
// 256 blocks x 256 thr. Block: batch-group bg (16 batches) x j-group jg (16 hidden).
// LDS: w_hh slice [64 n][1024 k] bf16 swizzled (128 KB) + gate buffer [4][16][16] f32.
// Wave w computes gate w. c in registers. One 2-level barrier per step per bg-group.
__global__ __launch_bounds__(256, 1) void k_lstm(
    const float* __restrict__ w_hh, const float* __restrict__ c0,
    const unsigned short* __restrict__ xg,
    unsigned short* __restrict__ hbuf,                  // [2][64][1024] bf16
    unsigned* __restrict__ cnt1, unsigned* __restrict__ cnt2,
    float* __restrict__ outH, float* __restrict__ outC) {
    extern __shared__ char smem[];
    unsigned short* w_lds = (unsigned short*)smem;      // 131072 B
    float* g_lds = (float*)(smem + 131072);             // 4096 B

    const unsigned L = blockIdx.x;
    const unsigned xcd = L & 7;
    const unsigned bg = xcd >> 1;
    const unsigned half = xcd & 1;
    const unsigned jg = (L >> 3) + 32u * half;          // 0..63
    const unsigned lb = bg * 64 + jg;                   // logical block id for xg layout
    const int tid = threadIdx.x, lane = tid & 63, w = tid >> 6;

    // fill w_lds: row nl -> global n = (nl>>4)*1024 + jg*16 + (nl&15); swizzle ^((nl&7)<<4)
    {
        const int nl = tid >> 2, qq = tid & 3;
        const int n = ((nl >> 4) << 10) + (int)jg * 16 + (nl & 15);
        const float4* src = (const float4*)(w_hh + (size_t)n * 1024 + qq * 256);
        const unsigned rbase = (unsigned)(nl * 2048 + qq * 512);
        const unsigned sw = (unsigned)((nl & 7) << 4);
        for (int i = 0; i < 64; i += 2) {
            float4 v0 = src[i], v1 = src[i + 1];
            short8 p;
            p[0] = (short)f2bf(v0.x); p[1] = (short)f2bf(v0.y);
            p[2] = (short)f2bf(v0.z); p[3] = (short)f2bf(v0.w);
            p[4] = (short)f2bf(v1.x); p[5] = (short)f2bf(v1.y);
            p[6] = (short)f2bf(v1.z); p[7] = (short)f2bf(v1.w);
            *(short8*)((char*)w_lds + ((rbase + (unsigned)i * 8u) ^ sw)) = p;
        }
    }

    const int bl = tid >> 4, jl = tid & 15;
    float c_reg = c0[(size_t)(bg * 16 + bl) * 1024 + jg * 16 + jl];
    float h_fin = 0.0f;

    const int r = lane & 15, kq = lane >> 4;
    const unsigned brow = (unsigned)(w * 16 + r);
    const unsigned bbyte_base = brow * 2048u + (unsigned)kq * 16u;
    const unsigned bswz = (brow & 7u) << 4;
    const size_t arow_off = (size_t)(bg * 16 + r) * 1024 + kq * 8;

    __syncthreads();

    for (int t = 0; t < T_STEPS; ++t) {
        const unsigned short* hp = hbuf + (size_t)(t & 1) * 65536;
        unsigned short* hn = hbuf + (size_t)((t + 1) & 1) * 65536;

        // prefetch this thread's 4 xg values (D-frag: col=r, rows kq*4+q)
        const unsigned short* xgp = xg + (((size_t)t * 256 + lb) * 4 + w) * 256;
        unsigned short xv[4];
        #pragma unroll
        for (int q = 0; q < 4; ++q) xv[q] = xgp[(kq * 4 + q) * 16 + r];

        f32x4 acc0 = {0.f, 0.f, 0.f, 0.f};
        f32x4 acc1 = {0.f, 0.f, 0.f, 0.f};
        const short8* ap = (const short8*)(hp + arow_off);
        #pragma unroll 4
        for (int kit = 0; kit < 16; ++kit) {
            short8 a0 = ap[kit * 4];
            short8 a1 = ap[64 + kit * 4];
            short8 b0 = *(const short8*)((char*)w_lds + ((bbyte_base + (unsigned)kit * 64u) ^ bswz));
            short8 b1 = *(const short8*)((char*)w_lds + ((bbyte_base + 1024u + (unsigned)kit * 64u) ^ bswz));
            acc0 = __builtin_amdgcn_mfma_f32_16x16x32_bf16(a0, b0, acc0, 0, 0, 0);
            acc1 = __builtin_amdgcn_mfma_f32_16x16x32_bf16(a1, b1, acc1, 0, 0, 0);
        }
        f32x4 acc = acc0 + acc1;
        #pragma unroll
        for (int q = 0; q < 4; ++q)
            g_lds[w * 256 + (kq * 4 + q) * 16 + r] = acc[q] + bf2f(xv[q]);
        __syncthreads();

        // elementwise cell update: thread -> (bl, jl)
        float gi = g_lds[0 * 256 + bl * 16 + jl];
        float gf = g_lds[1 * 256 + bl * 16 + jl];
        float gg = g_lds[2 * 256 + bl * 16 + jl];
        float go = g_lds[3 * 256 + bl * 16 + jl];
        c_reg = sigf(gf) * c_reg + sigf(gi) * tanhf_(gg);
        float h = sigf(go) * tanhf_(c_reg);
        h_fin = h;
        hn[(size_t)(bg * 16 + bl) * 1024 + jg * 16 + jl] = f2bf(h);

        __threadfence();          // publish h writes (device scope)
        __syncthreads();          // all waves' stores+fences done before arrival
        if (tid == 0) {
            unsigned i1 = ((unsigned)t * 4u + bg) * 2u + half;
            unsigned o1 = atomicAdd(&cnt1[i1], 1u);
            if (o1 == 31u) atomicAdd(&cnt2[(unsigned)t * 4u + bg], 1u);
            while (__hip_atomic_load(&cnt2[(unsigned)t * 4u + bg],
                                     __ATOMIC_RELAXED, __HIP_MEMORY_SCOPE_AGENT) < 2u)
                __builtin_amdgcn_s_sleep(2);
        }
        __syncthreads();
        __threadfence();          // acquire side: invalidate caches before reading new h
    }

    outH[(size_t)(bg * 16 + bl) * 1024 + jg * 16 + jl] = h_fin;
    outC[(size_t)(bg * 16 + bl) * 1024 + jg * 16 + jl] = c_reg;
}

// ---------------------------------------------------------------- launch
extern "C" void kernel_launch(void* const* d_in, const int* in_sizes, int n_in,
                              void* d_out, int out_size, void* d_ws, size_t ws_size,
                              hipStream_t stream) {
    const float* x    = (const float*)d_in[0];
    const float* h0   = (const float*)d_in[1];
    const float* c0   = (const float*)d_in[2];
    const float* w_ih = (const float*)d_in[3];
    const float* w_hh = (const float*)d_in[4];
    const float* b_ih = (const float*)d_in[5];
    const float* b_hh = (const float*)d_in[6];

    float* outH = (float*)d_out;
    float* outC = outH + 65536;

    uint8_t* ws = (uint8_t*)d_ws;
    unsigned short* xg   = (unsigned short*)ws;                          // 268,435,456 B
    unsigned short* wb   = (unsigned short*)(ws + 268435456ULL);         //   8,388,608 B
    float*          bias = (float*)(ws + 276824064ULL);                  //      16,384 B
    unsigned short* hbuf = (unsigned short*)(ws + 276840448ULL);         //     262,144 B
    unsigned*       cnt1 = (unsigned*)(ws + 277102592ULL);               //      16,384 B
    unsigned*       cnt2 = (unsigned*)(ws + 277118976ULL);               //       8,192 B

    k_setup<<<1024, 256, 0, stream>>>(w_ih, b_ih, b_hh, h0, wb, bias, hbuf, cnt1);
    k_gemm<<<8192, 256, 0, stream>>>(x, wb, bias, xg);

    hipFuncSetAttribute((const void*)k_lstm, hipFuncAttributeMaxDynamicSharedMemorySize, 135168);
    k_lstm<<<256, 256, 135168, stream>>>(w_hh, c0, xg, hbuf, cnt1, cnt2, outH, outC);
}

// Round 4
// 3612.491 us; speedup vs baseline: 5.9308x; 5.9308x over previous
//
#include <hip/hip_runtime.h>
#include <hip/hip_bf16.h>
#include <stdint.h>

// LSTM T=512 B=64 I=H=1024.
// Phase 1: xg = x @ w_ih^T + (b_ih+b_hh)  -- MFMA GEMM, bf16 out, permuted layout.
// Phase 2: persistent kernel, 256 blocks (1/CU). w_hh fragments pinned in VGPRs,
//          h tile staged in swizzled LDS, c in regs. Cross-block sync via
//          fine-grained agent-coherent (sc0 sc1) stores/loads + per-block flags.
//          NO threadfence / bulk cache ops.

typedef short  short8 __attribute__((ext_vector_type(8)));
typedef float  f32x4  __attribute__((ext_vector_type(4)));
typedef int    i32x4  __attribute__((ext_vector_type(4)));

#define T_STEPS 512

__device__ __forceinline__ unsigned short f2bf(float f) {
    uint32_t u = __float_as_uint(f);
    return (unsigned short)((u + 0x7fffu + ((u >> 16) & 1u)) >> 16);
}
__device__ __forceinline__ float bf2f(unsigned short v) {
    return __uint_as_float(((uint32_t)v) << 16);
}
__device__ __forceinline__ float sigf(float x)  { return 1.0f / (1.0f + __expf(-x)); }
__device__ __forceinline__ float tanhf_(float x){ return 1.0f - 2.0f / (__expf(2.0f * x) + 1.0f); }

// agent-coherent 16B load (bypasses L1+L2; data served from LLC/mem)
__device__ __forceinline__ i32x4 load16_agent(const void* p) {
    i32x4 r;
    asm volatile("global_load_dwordx4 %0, %1, off sc0 sc1"
                 : "=v"(r) : "v"(p) : "memory");
    return r;
}

// ---------------------------------------------------------------- setup
// w_ih -> bf16, bias = b_ih+b_hh, h0 -> bf16 into hbuf[0], zero flags.
__global__ void k_setup(const float* __restrict__ w_ih,
                        const float* __restrict__ b_ih, const float* __restrict__ b_hh,
                        const float* __restrict__ h0,
                        unsigned short* __restrict__ wb, float* __restrict__ bias,
                        unsigned short* __restrict__ hb0, unsigned* __restrict__ flags) {
    int idx = blockIdx.x * blockDim.x + threadIdx.x;
    int stride = gridDim.x * blockDim.x;
    const float4* w4 = (const float4*)w_ih;
    ushort4* wb4 = (ushort4*)wb;
    for (int i = idx; i < 1048576; i += stride) {       // 4096*1024/4
        float4 v = w4[i];
        wb4[i] = make_ushort4(f2bf(v.x), f2bf(v.y), f2bf(v.z), f2bf(v.w));
    }
    const float4* bi4 = (const float4*)b_ih;
    const float4* bh4 = (const float4*)b_hh;
    float4* bs4 = (float4*)bias;
    for (int i = idx; i < 1024; i += stride) {
        float4 a = bi4[i], b = bh4[i];
        bs4[i] = make_float4(a.x + b.x, a.y + b.y, a.z + b.z, a.w + b.w);
    }
    const float4* h04 = (const float4*)h0;
    ushort4* hb4 = (ushort4*)hb0;
    for (int i = idx; i < 16384; i += stride) {
        float4 v = h04[i];
        hb4[i] = make_ushort4(f2bf(v.x), f2bf(v.y), f2bf(v.z), f2bf(v.w));
    }
    for (int i = idx; i < 131072; i += stride) flags[i] = 0u;   // [512][4][64]
}

// ---------------------------------------------------------------- xg GEMM
// out[m][n] = sum_k x[m][k]*w_ih[n][k] + bias[n], m = t*64+b, n = g*1024+j.
// 128x128 tile, BK=64, 256 threads / 4 waves, each wave 4x4 16x16 frags.
// xg layout: [t][lb = bg*64+jg][g][ (b&15)*16 + jl ]  (2 KB per (t, block)).
__device__ __forceinline__ short8 lds_frag(const unsigned short* base, int row, int kbyte) {
    unsigned off = (unsigned)(row * 128 + kbyte);
    off ^= (unsigned)((row & 7) << 4);
    return *(const short8*)((const char*)base + off);
}

__global__ __launch_bounds__(256) void k_gemm(const float* __restrict__ x,
                                              const unsigned short* __restrict__ wb,
                                              const float* __restrict__ bias,
                                              unsigned short* __restrict__ xg) {
    __shared__ __align__(16) unsigned short As[128 * 64];
    __shared__ __align__(16) unsigned short Bs[128 * 64];
    unsigned orig = blockIdx.x;
    unsigned xcd = orig & 7, idx = orig >> 3;           // idx 0..1023
    unsigned n_t = xcd * 4 + (idx >> 8);                // 0..31
    unsigned m_t = idx & 255;                           // 0..255
    const int m0 = (int)m_t * 128, n0 = (int)n_t * 128;
    const int tid = threadIdx.x;
    const int lane = tid & 63, w = tid >> 6;
    const int wr = w >> 1, wc = w & 1;
    const int r = lane & 15, kq = lane >> 4;

    f32x4 acc[4][4] = {};

    const int ar = tid >> 1, ah = tid & 1;              // staging row / k-half

    for (int k0 = 0; k0 < 1024; k0 += 64) {
        {
            const float4* src = (const float4*)(x + (size_t)(m0 + ar) * 1024 + k0 + ah * 32);
            unsigned aw_base = (unsigned)(ar * 128 + ah * 64);
            unsigned sw = (unsigned)((ar & 7) << 4);
            #pragma unroll
            for (int i = 0; i < 4; ++i) {
                float4 v0 = src[2 * i], v1 = src[2 * i + 1];
                short8 p;
                p[0] = (short)f2bf(v0.x); p[1] = (short)f2bf(v0.y);
                p[2] = (short)f2bf(v0.z); p[3] = (short)f2bf(v0.w);
                p[4] = (short)f2bf(v1.x); p[5] = (short)f2bf(v1.y);
                p[6] = (short)f2bf(v1.z); p[7] = (short)f2bf(v1.w);
                *(short8*)((char*)As + ((aw_base + i * 16) ^ sw)) = p;
            }
        }
        {
            const short8* src = (const short8*)(wb + (size_t)(n0 + ar) * 1024 + k0 + ah * 32);
            unsigned bw_base = (unsigned)(ar * 128 + ah * 64);
            unsigned sw = (unsigned)((ar & 7) << 4);
            #pragma unroll
            for (int i = 0; i < 4; ++i) {
                short8 p = src[i];
                *(short8*)((char*)Bs + ((bw_base + i * 16) ^ sw)) = p;
            }
        }
        __syncthreads();
        #pragma unroll
        for (int kk = 0; kk < 2; ++kk) {
            short8 af[4], bfr[4];
            #pragma unroll
            for (int i = 0; i < 4; ++i) af[i]  = lds_frag(As, wr * 64 + i * 16 + r, (kk * 32 + kq * 8) * 2);
            #pragma unroll
            for (int j = 0; j < 4; ++j) bfr[j] = lds_frag(Bs, wc * 64 + j * 16 + r, (kk * 32 + kq * 8) * 2);
            #pragma unroll
            for (int i = 0; i < 4; ++i)
                #pragma unroll
                for (int j = 0; j < 4; ++j)
                    acc[i][j] = __builtin_amdgcn_mfma_f32_16x16x32_bf16(af[i], bfr[j], acc[i][j], 0, 0, 0);
        }
        __syncthreads();
    }

    const int t_idx = (m0 + wr * 64) >> 6;
    const size_t tb = (size_t)t_idx * 256;
    #pragma unroll
    for (int j = 0; j < 4; ++j) {
        int nn = n0 + wc * 64 + j * 16 + r;
        float bsum = bias[nn];
        int g = nn >> 10, jj = nn & 1023;
        int jgx = jj >> 4, jlx = jj & 15;
        #pragma unroll
        for (int i = 0; i < 4; ++i) {                   // i == bg
            size_t off = ((tb + (size_t)i * 64 + jgx) * 4 + g) * 256 + (size_t)(kq * 4) * 16 + jlx;
            #pragma unroll
            for (int q = 0; q < 4; ++q)
                xg[off + (size_t)q * 16] = f2bf(acc[i][j][q] + bsum);
        }
    }
}

// ---------------------------------------------------------------- persistent recurrence
// 256 blocks x 256 thr (4 waves). Block L: bg = L>>6 (16 batches), jg = L&63 (16 hidden).
// Wave w computes gate w; its 16 cols x K=1024 of w_hh live in bfrag[32] (128 VGPR).
// h tile (16 x 1024 bf16) staged per step into swizzled LDS via agent-coherent loads.
__global__ __launch_bounds__(256, 1) void k_lstm(
    const float* __restrict__ w_hh, const float* __restrict__ c0g,
    const unsigned short* __restrict__ xg,
    unsigned short* __restrict__ hbuf,                  // [2][64][1024] bf16
    unsigned* __restrict__ flags,                       // [512][4][64]
    float* __restrict__ outH, float* __restrict__ outC) {
    __shared__ __align__(16) unsigned short h_lds[16 * 1024];   // 32 KB
    __shared__ float g_lds[4 * 256];                            // 4 KB

    const unsigned L = blockIdx.x;
    const unsigned bg = L >> 6, jg = L & 63;
    const int tid = threadIdx.x, lane = tid & 63, w = tid >> 6;
    const int r = lane & 15, kq = lane >> 4;

    // ---- pin B fragments (w_hh, this wave's gate, cols jg*16..+16) in registers
    const int n = (w << 10) + (int)jg * 16 + r;
    short8 bfrag[32];
    {
        const float4* wrow = (const float4*)(w_hh + (size_t)n * 1024 + kq * 8);
        #pragma unroll
        for (int kit = 0; kit < 32; ++kit) {
            float4 v0 = wrow[kit * 8];
            float4 v1 = wrow[kit * 8 + 1];
            short8 p;
            p[0] = (short)f2bf(v0.x); p[1] = (short)f2bf(v0.y);
            p[2] = (short)f2bf(v0.z); p[3] = (short)f2bf(v0.w);
            p[4] = (short)f2bf(v1.x); p[5] = (short)f2bf(v1.y);
            p[6] = (short)f2bf(v1.z); p[7] = (short)f2bf(v1.w);
            bfrag[kit] = p;
        }
    }

    // ---- cell state: threads 0..127 own (bl = tid>>3, j pair jp = tid&7)
    const int bl = tid >> 3, jp = tid & 7;
    const size_t cellIdx = (size_t)(bg * 16 + (bl & 15)) * 1024 + jg * 16 + jp * 2;
    float c0r = 0.f, c1r = 0.f;
    if (tid < 128) { c0r = c0g[cellIdx]; c1r = c0g[cellIdx + 1]; }

    for (int t = 0; t < T_STEPS; ++t) {
        const unsigned short* hp = hbuf + (size_t)(t & 1) * 65536;
        unsigned short* hn = hbuf + (size_t)((t + 1) & 1) * 65536;

        // ---- wait for previous step's h (all 64 producer blocks of our bg)
        if (t > 0 && w == 0) {
            const unsigned* fl = flags + ((unsigned)(t - 1) * 4u + bg) * 64u;
            while (true) {
                unsigned f = __hip_atomic_load(fl + lane, __ATOMIC_RELAXED,
                                               __HIP_MEMORY_SCOPE_AGENT);
                if (__ballot(f != 0u) == ~0ull) break;
                __builtin_amdgcn_s_sleep(1);
            }
        }
        __syncthreads();

        // ---- stage h tile (our bg's 16 rows x 1024) into swizzled LDS
        {
            const char* src = (const char*)(hp + (size_t)bg * 16 * 1024);
            i32x4 stg[8];
            #pragma unroll
            for (int i = 0; i < 8; ++i)
                stg[i] = load16_agent(src + (unsigned)tid * 16u + (unsigned)i * 4096u);
            asm volatile("s_waitcnt vmcnt(0)" ::: "memory");
            __builtin_amdgcn_sched_barrier(0);
            #pragma unroll
            for (int i = 0; i < 8; ++i) {
                unsigned off = (unsigned)tid * 16u + (unsigned)i * 4096u;
                unsigned row = off >> 11, colb = off & 2047u;
                *(i32x4*)((char*)h_lds + row * 2048u + (colb ^ ((row & 7u) << 4))) = stg[i];
            }
        }
        __syncthreads();

        // ---- xg prefetch (this wave's gate fragment)
        const unsigned short* xgp = xg + (((size_t)t * 256 + L) * 4 + w) * 256;
        float xv[4];
        #pragma unroll
        for (int q = 0; q < 4; ++q) xv[q] = bf2f(xgp[(kq * 4 + q) * 16 + r]);

        // ---- gates = h @ w_hh^T : 32 MFMAs, 2 independent chains
        f32x4 acc0 = {0.f, 0.f, 0.f, 0.f}, acc1 = {0.f, 0.f, 0.f, 0.f};
        const char* arow = (const char*)h_lds + (unsigned)r * 2048u;
        const unsigned asw = ((unsigned)(r & 7)) << 4;
        #pragma unroll
        for (int kit = 0; kit < 32; kit += 2) {
            short8 a0 = *(const short8*)(arow + (((unsigned)kit * 64u + (unsigned)kq * 16u) ^ asw));
            short8 a1 = *(const short8*)(arow + (((unsigned)(kit + 1) * 64u + (unsigned)kq * 16u) ^ asw));
            acc0 = __builtin_amdgcn_mfma_f32_16x16x32_bf16(a0, bfrag[kit], acc0, 0, 0, 0);
            acc1 = __builtin_amdgcn_mfma_f32_16x16x32_bf16(a1, bfrag[kit + 1], acc1, 0, 0, 0);
        }
        f32x4 acc = acc0 + acc1;
        #pragma unroll
        for (int q = 0; q < 4; ++q)
            g_lds[w * 256 + (kq * 4 + q) * 16 + r] = acc[q] + xv[q];
        __syncthreads();

        // ---- cell update (threads 0..127, two j's each), coherent h store
        if (tid < 128) {
            int gb = (bl & 15) * 16 + jp * 2;
            float gi0 = g_lds[gb],       gi1 = g_lds[gb + 1];
            float gf0 = g_lds[256 + gb], gf1 = g_lds[256 + gb + 1];
            float gg0 = g_lds[512 + gb], gg1 = g_lds[512 + gb + 1];
            float go0 = g_lds[768 + gb], go1 = g_lds[768 + gb + 1];
            c0r = sigf(gf0) * c0r + sigf(gi0) * tanhf_(gg0);
            c1r = sigf(gf1) * c1r + sigf(gi1) * tanhf_(gg1);
            float h0v = sigf(go0) * tanhf_(c0r);
            float h1v = sigf(go1) * tanhf_(c1r);
            unsigned packed = (unsigned)f2bf(h0v) | ((unsigned)f2bf(h1v) << 16);
            __hip_atomic_store((unsigned*)(hn + cellIdx), packed,
                               __ATOMIC_RELAXED, __HIP_MEMORY_SCOPE_AGENT);
            if (t == T_STEPS - 1) {
                outH[cellIdx] = h0v; outH[cellIdx + 1] = h1v;
                outC[cellIdx] = c0r; outC[cellIdx + 1] = c1r;
            }
        }
        asm volatile("s_waitcnt vmcnt(0)" ::: "memory");   // h stores at LLC
        __syncthreads();                                    // whole block done
        if (tid == 0)
            __hip_atomic_store(flags + ((unsigned)t * 4u + bg) * 64u + jg, 1u,
                               __ATOMIC_RELAXED, __HIP_MEMORY_SCOPE_AGENT);
    }
}

// ---------------------------------------------------------------- launch
extern "C" void kernel_launch(void* const* d_in, const int* in_sizes, int n_in,
                              void* d_out, int out_size, void* d_ws, size_t ws_size,
                              hipStream_t stream) {
    const float* x    = (const float*)d_in[0];
    const float* h0   = (const float*)d_in[1];
    const float* c0   = (const float*)d_in[2];
    const float* w_ih = (const float*)d_in[3];
    const float* w_hh = (const float*)d_in[4];
    const float* b_ih = (const float*)d_in[5];
    const float* b_hh = (const float*)d_in[6];

    float* outH = (float*)d_out;
    float* outC = outH + 65536;

    uint8_t* ws = (uint8_t*)d_ws;
    unsigned short* xg    = (unsigned short*)ws;                         // 268,435,456 B
    unsigned short* wb    = (unsigned short*)(ws + 268435456ULL);        //   8,388,608 B
    float*          bias  = (float*)(ws + 276824064ULL);                 //      16,384 B
    unsigned short* hbuf  = (unsigned short*)(ws + 276840448ULL);        //     262,144 B
    unsigned*       flags = (unsigned*)(ws + 277102592ULL);              //     524,288 B

    k_setup<<<1024, 256, 0, stream>>>(w_ih, b_ih, b_hh, h0, wb, bias, hbuf, flags);
    k_gemm<<<8192, 256, 0, stream>>>(x, wb, bias, xg);
    k_lstm<<<256, 256, 0, stream>>>(w_hh, c0, xg, hbuf, flags, outH, outC);
}